// Round 21
// baseline (350.029 us; speedup 1.0000x reference)
//
#include <hip/hip_runtime.h>
#include <hip/hip_bf16.h>

typedef unsigned short u16;
typedef short s16x8 __attribute__((ext_vector_type(8)));
typedef float f32x4 __attribute__((ext_vector_type(4)));
typedef float f32x8 __attribute__((ext_vector_type(8)));
typedef u16 u16x8 __attribute__((ext_vector_type(8)));

#define DEV static __device__ __forceinline__

DEV float b2f(u16 u){ unsigned int i=((unsigned int)u)<<16; float f; __builtin_memcpy(&f,&i,4); return f; }
DEV u16 f2b(float x){ __hip_bfloat16 h=__float2bfloat16(x); u16 u; __builtin_memcpy(&u,&h,2); return u; }
DEV f32x4 MFMA(s16x8 a, s16x8 b, f32x4 c){ return __builtin_amdgcn_mfma_f32_16x16x32_bf16(a,b,c,0,0,0); }
DEV s16x8 LD8(const u16* p){ return *(const s16x8*)p; }
// sigmoid-form gelu: x*sigmoid(1.702x). |dev from erf-gelu| <= 0.005 for |x|<1.5
DEV float gelu_fast(float x){
  return x / (1.f + __expf(-1.702f*x));
}
DEV float sigmf(float x){ return 1.0f/(1.0f+__expf(-x)); }

// async global->LDS, 16B per lane. LDS dest must be wave-uniform base (HW adds lane*16).
DEV void gload16(const u16* g, u16* l){
  __builtin_amdgcn_global_load_lds((const __attribute__((address_space(1))) void*)g,
                                   (__attribute__((address_space(3))) void*)l, 16, 0, 0);
}

// ---------------- workspace layout (u16 elements) ----------------
#define WS_WeT   0
#define WS_W1T   65536
#define WS_W2T   327680
#define WS_WmT   589824
#define WS_WvT   655360
#define WS_WoT   917504
#define WS_WgoT  1048576
#define WS_nW1T  1572864
#define WS_nW2T  2621440
#define WS_SrcT  3670016
#define WS_TgtT  3801088
#define WS_GateT 3932160
#define WS_GgT   4063232
#define WS_NM    4587520
#define WS_TGT   5111808
#define WS_GP    5636096
#define WS_GG    6160384
#define WS_MSG   8257536
// U2 / X / Y alias the MSG region (MSG dead after k_attn2)
#define WS_U2    8257536
#define WS_X     10354688   /* f32 region: 1,048,576 floats */
#define WS_Y     12451840
#define WS_WM    25034752
#define WS_U1    33423360
#define WS_YE    33947648   /* edge-LN Y; later AB f32 [65536][16] */
#define WS_H     50724864   /* node bf16 (early); edge-MLP hidden; Tm; node-MLP H2 */
// total 84,279,296 u16 = 168.6 MB

// ---------------- transpose + bf16-cast all weights ----------------
struct P13 { const float* p[13]; };
__device__ const int TR_START[14] = {0,16,80,144,160,224,256,384,640,896,928,960,992,1120};
__device__ const int TR_R[13]   = {256,256,1024,256,256,256,1024,512,2048,512,512,512,512};
__device__ const int TR_C[13]   = {256,1024,256,256,1024,512,512,2048,512,256,256,256,1024};
__device__ const int TR_DST[13] = {WS_WeT,WS_W1T,WS_W2T,WS_WmT,WS_WvT,WS_WoT,WS_WgoT,
                                   WS_nW1T,WS_nW2T,WS_SrcT,WS_TgtT,WS_GateT,WS_GgT};

__global__ __launch_bounds__(256) void k_transpose(P13 ps, u16* __restrict__ ws){
  __shared__ alignas(16) u16 Ts[64][72];
  const int t = threadIdx.x;
  int bid = blockIdx.x;
  int mi = 0;
  #pragma unroll 1
  while (bid >= TR_START[mi+1]) ++mi;
  const float* src = ps.p[mi];
  const int R = TR_R[mi], C = TR_C[mi];
  u16* dst = ws + TR_DST[mi];
  const int ti = bid - TR_START[mi];
  const int tcn = C >> 6;
  const int tr = ti / tcn, tc = ti % tcn;
  {
    const int row = t >> 2, cs = (t & 3) * 16;
    const float* sp = src + (tr*64 + row)*C + tc*64 + cs;
    u16x8 a, b;
    #pragma unroll
    for (int i=0;i<8;i++){ a[i]=f2b(sp[i]); b[i]=f2b(sp[8+i]); }
    *(u16x8*)&Ts[row][cs]   = a;
    *(u16x8*)&Ts[row][cs+8] = b;
  }
  __syncthreads();
  {
    const int col = t >> 2, rs = (t & 3) * 16;
    u16x8 a, b;
    #pragma unroll
    for (int i=0;i<8;i++){ a[i]=Ts[rs+i][col]; b[i]=Ts[rs+8+i][col]; }
    u16* dp = dst + (tc*64 + col)*R + tr*64 + rs;
    *(u16x8*)dp = a;
    *(u16x8*)(dp+8) = b;
  }
}

// ---------------- k_cvtnode: node_repr f32 -> bf16 (into WS_H, used by k_proj only) ----------------
__global__ __launch_bounds__(256) void k_cvtnode(const float* __restrict__ src, u16* __restrict__ dst){
  const int i = (blockIdx.x*256 + threadIdx.x)*8;
  f32x8 v = *(const f32x8*)(src + i);
  u16x8 o;
  #pragma unroll
  for (int j=0;j<8;j++) o[j] = f2b(v[j]);
  *(u16x8*)(dst + i) = o;
}

// ---------------- k_proj: node projections + gates (A from bf16 node) ----------------
__global__ __launch_bounds__(256) void k_proj(const float* __restrict__ bgate,
                                              const float* __restrict__ bgg,
                                              u16* __restrict__ ws){
  const int t=threadIdx.x, lid=t&63, w=t>>6, g=lid>>4, q=lid&15;
  const int rb = blockIdx.x, yb = blockIdx.y;
  const u16* nb = ws + WS_H;   // node bf16 [2048][512]
  const u16* BT; u16* dst; int Nseg, colbase, act=0; const float* bias=nullptr;
  if (yb < 4){ BT=ws+WS_SrcT;  dst=ws+WS_NM; Nseg=256;  colbase=yb*64; }
  else if (yb < 8){ BT=ws+WS_TgtT;  dst=ws+WS_TGT; Nseg=256; colbase=(yb-4)*64; }
  else if (yb < 12){ BT=ws+WS_GateT; dst=ws+WS_GP; Nseg=256; colbase=(yb-8)*64; act=1; bias=bgate; }
  else { BT=ws+WS_GgT; dst=ws+WS_GG; Nseg=1024; colbase=(yb-12)*64; act=1; bias=bgg; }
  const int wr=(w>>1)*32, wcl=(w&1)*32;
  f32x4 acc[2][2] = {};
  for (int kk=0; kk<512; kk+=32){
    s16x8 af[2], bfr[2];
    #pragma unroll
    for (int i=0;i<2;i++) af[i] = LD8(nb + (rb*64 + wr + i*16 + q)*512 + kk + 8*g);
    #pragma unroll
    for (int j=0;j<2;j++) bfr[j] = LD8(BT + (colbase + wcl + j*16 + q)*512 + kk + 8*g);
    #pragma unroll
    for (int i=0;i<2;i++)
      #pragma unroll
      for (int j=0;j<2;j++) acc[i][j] = MFMA(af[i], bfr[j], acc[i][j]);
  }
  #pragma unroll
  for (int i=0;i<2;i++)
    #pragma unroll
    for (int j=0;j<2;j++)
      #pragma unroll
      for (int r=0;r<4;r++){
        const int row = rb*64 + wr + i*16 + g*4 + r;
        const int col = wcl + j*16 + q;
        float v = acc[i][j][r];
        if (act) v = sigmf(v + bias[colbase+col]);
        dst[row*Nseg + colbase + col] = f2b(v);
      }
}

// ---------------- k_edgepre: 512-thread (8-wave), acc[2][4]=32 VGPR/thread ----------------
#define GB_S 528
__global__ __launch_bounds__(512) void k_edgepre(
    const float* __restrict__ edge_repr, const int* __restrict__ edge_index,
    const float* __restrict__ mask_bw,
    const float* __restrict__ ln_g, const float* __restrict__ ln_b,
    u16* __restrict__ ws)
{
  __shared__ alignas(16) char SH[64*GB_S];   // Gb (gather) / As+Bs (GEMM) / Ye stage
  __shared__ float rsS[4][64], rsQ[4][64];
  __shared__ int idxL[64]; __shared__ float mbwL[64];

  const int t=threadIdx.x, lid=t&63, w=t>>6, g=lid>>4, q=lid&15;
  const int R0 = blockIdx.x * 64;
  const int wrg = (w>>2)*32;       // row group: 0 or 32
  const int wcl = (w&3)*64;        // col group: 0,64,128,192
  u16* As = (u16*)SH;            // [64][32]
  u16* Bs = (u16*)(SH + 4096);   // [256][32]

  if (t < 64){
    idxL[t] = edge_index[R0+t];
    mbwL[t] = mask_bw[R0+t];
  }
  __syncthreads();

  const u16* nm = ws + WS_NM;
  const u16* tg = ws + WS_TGT;
  // vectorized gather staging into SH (as Gb): 2048 segs / 512 threads = 4 iters
  #pragma unroll
  for (int it=0; it<4; ++it){
    const int v = t + 512*it;
    const int row = v >> 5;
    const int sc  = (v & 31) * 8;
    const int er  = R0 + row;
    const int gnd = er >> 5;
    const int bi  = gnd >> 10;
    const int srow = bi*1024 + idxL[row];
    const float mb = mbwL[row];
    u16x8 nv = *(const u16x8*)(nm + srow*256 + sc);
    u16x8 tv = *(const u16x8*)(tg + gnd*256 + sc);
    u16x8 ov;
    #pragma unroll
    for (int j2=0;j2<8;j2++) ov[j2] = f2b(b2f(nv[j2])*mb + b2f(tv[j2]));
    *(u16x8*)(SH + row*GB_S + 2*sc) = ov;
  }
  __syncthreads();
  // acc init from staged gather; Gb dead afterwards
  f32x4 acc[2][4];
  #pragma unroll
  for (int i=0;i<2;i++)
    #pragma unroll
    for (int r=0;r<4;r++){
      const int row = wrg + i*16 + g*4 + r;
      #pragma unroll
      for (int j=0;j<4;j++){
        const int col = wcl + j*16 + q;
        acc[i][j][r] = b2f(*(const u16*)(SH + row*GB_S + 2*col));
      }
    }
  // pre-GEMM (SH reused as As/Bs)
  for (int kk=0; kk<256; kk+=32){
    __syncthreads();
    if (t < 256){
      const int row = t >> 2, c0 = (t & 3) * 8;
      const float* sp = edge_repr + (R0 + row)*256 + kk + c0;
      f32x8 fv = *(const f32x8*)sp;
      u16x8 av;
      #pragma unroll
      for (int j2=0;j2<8;j2++) av[j2] = f2b(fv[j2]);
      *(u16x8*)(As + row*32 + c0) = av;
    }
    #pragma unroll
    for (int j=0;j<2;j++){
      const int s = t + 512*j;
      const int brow = s >> 2, ko = (s & 3) * 8;
      u16* ldsB = Bs + (512*j + w*64)*8;
      gload16(ws + WS_WeT + brow*256 + kk + ko, ldsB);
    }
    __syncthreads();
    s16x8 af[2], bfr[4];
    #pragma unroll
    for (int i=0;i<2;i++) af[i]  = *(const s16x8*)(As + (wrg + i*16 + q)*32 + g*8);
    #pragma unroll
    for (int j=0;j<4;j++) bfr[j] = *(const s16x8*)(Bs + (wcl + j*16 + q)*32 + g*8);
    #pragma unroll
    for (int i=0;i<2;i++)
      #pragma unroll
      for (int j=0;j<4;j++) acc[i][j] = MFMA(af[i], bfr[j], acc[i][j]);
  }
  // LayerNorm over 256 (4 col-waves share each row group)
  #pragma unroll
  for (int i=0;i<2;i++)
    #pragma unroll
    for (int r=0;r<4;r++){
      float s=0.f, s2=0.f;
      #pragma unroll
      for (int j=0;j<4;j++){ float v=acc[i][j][r]; s+=v; s2+=v*v; }
      #pragma unroll
      for (int m=1;m<16;m<<=1){ s += __shfl_xor(s,m,64); s2 += __shfl_xor(s2,m,64); }
      if (q==0){ const int row=wrg+i*16+g*4+r; rsS[w&3][row]=s; rsQ[w&3][row]=s2; }
    }
  __syncthreads();   // As/Bs reads done -> SH free for Ye staging
  // LN values staged into SH (Gb layout), then coalesced copy-out
  #pragma unroll
  for (int i=0;i<2;i++)
    #pragma unroll
    for (int r=0;r<4;r++){
      const int row = wrg + i*16 + g*4 + r;
      const float s  = rsS[0][row]+rsS[1][row]+rsS[2][row]+rsS[3][row];
      const float s2 = rsQ[0][row]+rsQ[1][row]+rsQ[2][row]+rsQ[3][row];
      const float mean = s*(1.f/256.f);
      const float var  = s2*(1.f/256.f) - mean*mean;
      const float rstd = rsqrtf(var + 1e-5f);
      #pragma unroll
      for (int j=0;j<4;j++){
        const int col = wcl + j*16 + q;
        *(u16*)(SH + row*GB_S + 2*col) = f2b((acc[i][j][r]-mean)*rstd*ln_g[col] + ln_b[col]);
      }
    }
  __syncthreads();
  u16* Ye = ws + WS_YE;
  #pragma unroll
  for (int it=0; it<4; ++it){
    const int v = t + 512*it;
    const int row = v >> 5, sc = (v & 31)*8;
    *(u16x8*)(Ye + (R0+row)*256 + sc) = *(const u16x8*)(SH + row*GB_S + 2*sc);
  }
}

// ---------------- k_mlp1: H = gelu(Y @ W1 + b1) ; col-slab, double-buffered T3-lite ----------------
__global__ __launch_bounds__(256) void k_mlp1(const u16* __restrict__ A,
                                              const u16* __restrict__ BT,
                                              const float* __restrict__ b1,
                                              u16* __restrict__ H){
  __shared__ alignas(16) u16 SH2[16384];   // 32KB: 2x(As[128][32]+Bs[128][32]); epilogue reuses [0..8704)
  const int t=threadIdx.x, lid=t&63, w=t>>6, g=lid>>4, q=lid&15;
  const int r0 = blockIdx.x*128, n0 = blockIdx.y*128;
  const int wc3 = w*32;
  f32x4 acc[8][2] = {};
  // prologue: stage buffer 0 with kk=0
  #pragma unroll
  for (int j=0;j<2;j++){
    const int v = t + 256*j;
    const int row = v>>2, sg = (v&3)*8;
    gload16(A  + (r0+row)*256 + sg,        SH2 + (w*64 + 256*j)*8);
    gload16(BT + (n0+row)*256 + sg,        SH2 + 4096 + (w*64 + 256*j)*8);
  }
  __syncthreads();
  for (int ks=0; ks<8; ++ks){
    const int cur = ks & 1;
    if (ks < 7){
      const int kk = (ks+1)*32;
      const int nb = cur ^ 1;
      #pragma unroll
      for (int j=0;j<2;j++){
        const int v = t + 256*j;
        const int row = v>>2, sg = (v&3)*8;
        gload16(A  + (r0+row)*256 + kk + sg, SH2 + nb*8192 + (w*64 + 256*j)*8);
        gload16(BT + (n0+row)*256 + kk + sg, SH2 + nb*8192 + 4096 + (w*64 + 256*j)*8);
      }
    }
    const u16* As = SH2 + cur*8192;
    const u16* Bs = As + 4096;
    s16x8 bf_[2];
    #pragma unroll
    for (int j=0;j<2;j++) bf_[j] = *(const s16x8*)(Bs + (wc3 + j*16 + q)*32 + g*8);
    #pragma unroll
    for (int i=0;i<8;i++){
      s16x8 af = *(const s16x8*)(As + (i*16+q)*32 + g*8);
      #pragma unroll
      for (int j=0;j<2;j++) acc[i][j] = MFMA(af, bf_[j], acc[i][j]);
    }
    __syncthreads();   // drains next-tile gloads; frees cur for ks+2
  }
  // staged epilogue: 2 passes of 64 rows through SH2[0..64*136)
  #pragma unroll
  for (int p=0;p<2;p++){
    __syncthreads();
    #pragma unroll
    for (int i2=0;i2<4;i2++)
      #pragma unroll
      for (int j=0;j<2;j++)
        #pragma unroll
        for (int r=0;r<4;r++){
          const int rl = i2*16 + g*4 + r;
          const int cl = wc3 + j*16 + q;
          SH2[rl*136 + cl] = f2b(gelu_fast(acc[p*4+i2][j][r] + b1[n0 + cl]));
        }
    __syncthreads();
    #pragma unroll
    for (int it=0; it<4; ++it){
      const int v = t + 256*it;
      const int rrow = v >> 4, sc = (v & 15)*8;
      *(u16x8*)(H + (r0 + p*64 + rrow)*1024 + n0 + sc) = *(const u16x8*)(SH2 + rrow*136 + sc);
    }
  }
}

// ---------------- k_mlp2: msg = mask * (H @ W2 + b2) ; quadrant, double-buffered T3-lite ----------------
__global__ __launch_bounds__(256) void k_mlp2(const u16* __restrict__ A,
                                              const u16* __restrict__ BT,
                                              const float* __restrict__ b2,
                                              const int* __restrict__ em,
                                              u16* __restrict__ msg){
  __shared__ alignas(16) u16 SH2[16384];   // 32KB: 2x(As[128][32]+Bs[128][32])
  __shared__ int emL[128];
  const int t=threadIdx.x, lid=t&63, w=t>>6, g=lid>>4, q=lid&15;
  const int r0 = blockIdx.x*128, n0 = blockIdx.y*128;
  const int wr=(w>>1)*64, wc2=(w&1)*64;
  if (t < 128) emL[t] = em[r0 + t];
  f32x4 acc[4][4] = {};
  // prologue: stage buffer 0 with kk=0
  #pragma unroll
  for (int j=0;j<2;j++){
    const int v = t + 256*j;
    const int row = v>>2, sg = (v&3)*8;
    gload16(A  + (r0+row)*1024 + sg, SH2 + (w*64 + 256*j)*8);
    gload16(BT + (n0+row)*1024 + sg, SH2 + 4096 + (w*64 + 256*j)*8);
  }
  __syncthreads();
  for (int ks=0; ks<32; ++ks){
    const int cur = ks & 1;
    if (ks < 31){
      const int kk = (ks+1)*32;
      const int nb = cur ^ 1;
      #pragma unroll
      for (int j=0;j<2;j++){
        const int v = t + 256*j;
        const int row = v>>2, sg = (v&3)*8;
        gload16(A  + (r0+row)*1024 + kk + sg, SH2 + nb*8192 + (w*64 + 256*j)*8);
        gload16(BT + (n0+row)*1024 + kk + sg, SH2 + nb*8192 + 4096 + (w*64 + 256*j)*8);
      }
    }
    const u16* As = SH2 + cur*8192;
    const u16* Bs = As + 4096;
    s16x8 af[4], bf_[4];
    #pragma unroll
    for (int i=0;i<4;i++) af[i]  = *(const s16x8*)(As + (wr+i*16+q)*32 + g*8);
    #pragma unroll
    for (int j=0;j<4;j++) bf_[j] = *(const s16x8*)(Bs + (wc2+j*16+q)*32 + g*8);
    #pragma unroll
    for (int i=0;i<4;i++)
      #pragma unroll
      for (int j=0;j<4;j++) acc[i][j] = MFMA(af[i], bf_[j], acc[i][j]);
    __syncthreads();
  }
  #pragma unroll
  for (int i=0;i<4;i++)
    #pragma unroll
    for (int j=0;j<4;j++)
      #pragma unroll
      for (int r=0;r<4;r++){
        const int rl  = wr + i*16 + g*4 + r;
        const int col = n0 + wc2 + j*16 + q;
        float v = acc[i][j][r] + b2[col];
        if (!emL[rl]) v = 0.f;
        msg[(r0+rl)*256 + col] = f2b(v);
      }
}

// ---------------- k_tm: Tm = lrelu(msg @ Wm) ; col-slab, double-buffered T3-lite ----------------
__global__ __launch_bounds__(256) void k_tm(const u16* __restrict__ A,
                                            const u16* __restrict__ BT,
                                            u16* __restrict__ Tm){
  __shared__ alignas(16) u16 SH2[16384];
  const int t=threadIdx.x, lid=t&63, w=t>>6, g=lid>>4, q=lid&15;
  const int r0 = blockIdx.x*128, n0 = blockIdx.y*128;
  const int wc3 = w*32;
  f32x4 acc[8][2] = {};
  #pragma unroll
  for (int j=0;j<2;j++){
    const int v = t + 256*j;
    const int row = v>>2, sg = (v&3)*8;
    gload16(A  + (r0+row)*256 + sg, SH2 + (w*64 + 256*j)*8);
    gload16(BT + (n0+row)*256 + sg, SH2 + 4096 + (w*64 + 256*j)*8);
  }
  __syncthreads();
  for (int ks=0; ks<8; ++ks){
    const int cur = ks & 1;
    if (ks < 7){
      const int kk = (ks+1)*32;
      const int nb = cur ^ 1;
      #pragma unroll
      for (int j=0;j<2;j++){
        const int v = t + 256*j;
        const int row = v>>2, sg = (v&3)*8;
        gload16(A  + (r0+row)*256 + kk + sg, SH2 + nb*8192 + (w*64 + 256*j)*8);
        gload16(BT + (n0+row)*256 + kk + sg, SH2 + nb*8192 + 4096 + (w*64 + 256*j)*8);
      }
    }
    const u16* As = SH2 + cur*8192;
    const u16* Bs = As + 4096;
    s16x8 bf_[2];
    #pragma unroll
    for (int j=0;j<2;j++) bf_[j] = *(const s16x8*)(Bs + (wc3 + j*16 + q)*32 + g*8);
    #pragma unroll
    for (int i=0;i<8;i++){
      s16x8 af = *(const s16x8*)(As + (i*16+q)*32 + g*8);
      #pragma unroll
      for (int j=0;j<2;j++) acc[i][j] = MFMA(af, bf_[j], acc[i][j]);
    }
    __syncthreads();
  }
  #pragma unroll
  for (int p=0;p<2;p++){
    __syncthreads();
    #pragma unroll
    for (int i2=0;i2<4;i2++)
      #pragma unroll
      for (int j=0;j<2;j++)
        #pragma unroll
        for (int r=0;r<4;r++){
          const int rl = i2*16 + g*4 + r;
          const int cl = wc3 + j*16 + q;
          float v = acc[p*4+i2][j][r];
          SH2[rl*136 + cl] = f2b(v > 0.f ? v : 0.01f*v);
        }
    __syncthreads();
    #pragma unroll
    for (int it=0; it<4; ++it){
      const int v = t + 256*it;
      const int rrow = v >> 4, sc = (v & 15)*8;
      *(u16x8*)(Tm + (r0 + p*64 + rrow)*256 + n0 + sc) = *(const u16x8*)(SH2 + rrow*136 + sc);
    }
  }
}

// ---------------- k_ab: AB = Tm @ Wab ; 128-row x 16-col tiles ----------------
__global__ __launch_bounds__(256) void k_ab(const u16* __restrict__ A,
                                            const float* __restrict__ Wab,
                                            float* __restrict__ AB){
  __shared__ alignas(16) u16 As[128*32];
  __shared__ alignas(16) char WbT[16*528];
  const int t=threadIdx.x, lid=t&63, w=t>>6, g=lid>>4, q=lid&15;
  const int r0 = blockIdx.x*128;
  {
    const float* wr_ = Wab + t*16;
    #pragma unroll
    for (int h=0;h<16;h++) *(u16*)(WbT + h*528 + 2*t) = f2b(wr_[h]);
  }
  f32x4 acc[2] = {};
  for (int kk=0;kk<256;kk+=32){
    __syncthreads();
    #pragma unroll
    for (int j=0;j<2;j++){
      const int s = t + 256*j;
      const int row = s>>2, ko = (s&3)*8;
      gload16(A + (r0+row)*256 + kk + ko, As + (w*64 + 256*j)*8);
    }
    __syncthreads();
    s16x8 bf_ = *(const s16x8*)(WbT + q*528 + 2*(kk + 8*g));
    #pragma unroll
    for (int i=0;i<2;i++){
      s16x8 af = *(const s16x8*)(As + (w*32 + i*16 + q)*32 + g*8);
      acc[i] = MFMA(af, bf_, acc[i]);
    }
  }
  #pragma unroll
  for (int i=0;i<2;i++)
    #pragma unroll
    for (int r=0;r<4;r++){
      const int row = r0 + w*32 + i*16 + g*4 + r;
      AB[row*16 + q] = acc[i][r];
    }
}

// ---------------- k_attn2: per-node softmax + wm + pool (light) ----------------
#define AM_S 528
#define MT_S 80
__global__ __launch_bounds__(256) void k_attn2(const int* __restrict__ edge_mask,
                                               u16* __restrict__ ws){
  __shared__ alignas(16) char Am[32*AM_S];
  __shared__ alignas(16) char Mt[256*MT_S];
  __shared__ alignas(16) char Pb[16*80];
  __shared__ float Pp[32][16];
  __shared__ int emL[32];
  __shared__ float cntS;

  const int t=threadIdx.x, lid=t&63, w=t>>6, g=lid>>4, q=lid&15;
  const int nd = blockIdx.x;
  const int wc = w*64;
  const u16* msg = ws + WS_MSG + nd*32*256;
  const float* ab = (const float*)(ws + WS_YE) + nd*32*16;

  if (t < 32) emL[t] = edge_mask[nd*32 + t];
  #pragma unroll
  for (int it=0; it<4; ++it){
    const int v = t + 256*it;
    const int row = v >> 5, sc = (v & 31)*8;
    u16x8 val = *(const u16x8*)(msg + row*256 + sc);
    *(u16x8*)(Am + row*AM_S + 2*sc) = val;
  }
  {
    const int k = t >> 4, h = t & 15;
    Pp[k][h]    = ab[k*16 + h];
    Pp[k+16][h] = ab[(k+16)*16 + h];
  }
  __syncthreads();
  if (t == 0){ float c=0.f; for (int k=0;k<32;k++) c += emL[k]?1.f:0.f; cntS=c; }
  {
    const int c = t;
    #pragma unroll 1
    for (int k=0;k<32;k++){
      u16 vv = *(const u16*)(Am + k*AM_S + 2*c);
      *(u16*)(Mt + c*MT_S + 2*k) = vv;
    }
  }
  if (t < 16){
    const int h = t;
    float m = -3.4028235e38f;
    float pv[32];
    for (int k=0;k<32;k++){ pv[k] = emL[k] ? Pp[k][h] : -3.4028235e38f; m = fmaxf(m, pv[k]); }
    float s = 0.f;
    float ev[32];
    for (int k=0;k<32;k++){ ev[k]=__expf(pv[k]-m); s+=ev[k]; }
    const float inv = 1.f/s;
    for (int k=0;k<32;k++) *(u16*)(Pb + h*80 + 2*k) = f2b(ev[k]*inv);
  }
  __syncthreads();
  {
    s16x8 pa = *(const s16x8*)(Pb + q*80 + 2*(8*g));
    f32x4 wmac[4] = {};
    #pragma unroll
    for (int j=0;j<4;j++){
      s16x8 mb = *(const s16x8*)(Mt + (wc + j*16 + q)*MT_S + 2*(8*g));
      wmac[j] = MFMA(pa, mb, wmac[j]);
    }
    u16* wmw = ws + WS_WM;
    #pragma unroll
    for (int j=0;j<4;j++)
      #pragma unroll
      for (int r=0;r<4;r++){
        const int hh = g*4 + r;
        const int col = wc + j*16 + q;
        wmw[hh*(2048*256) + nd*256 + col] = f2b(wmac[j][r]);
      }
  }
  {
    const int c = t;
    float s = 0.f;
    #pragma unroll 1
    for (int k=0;k<32;k++) s += b2f(*(const u16*)(Am + k*AM_S + 2*c));
    const float o = s / (cntS + 1e-6f);
    ws[WS_U1 + nd*256 + c] = f2b(o * b2f(ws[WS_GP + nd*256 + c]));
  }
}

// ---------------- k_og: per-head value GEMM + gate -> U2 ----------------
__global__ __launch_bounds__(256) void k_og(u16* __restrict__ ws){
  const int t=threadIdx.x, lid=t&63, w=t>>6, g=lid>>4, q=lid&15;
  const int rb=blockIdx.x, h=blockIdx.y;
  const int wr=(w>>1)*32, wcl=(w&1)*32;
  const u16* A  = ws + WS_WM  + h*(2048*256);
  const u16* BT = ws + WS_WvT;
  f32x4 acc[2][2] = {};
  for (int kk=0;kk<256;kk+=32){
    s16x8 af[2], bfr[2];
    #pragma unroll
    for (int i=0;i<2;i++) af[i] = LD8(A + (rb*64 + wr + i*16 + q)*256 + kk + 8*g);
    #pragma unroll
    for (int j=0;j<2;j++) bfr[j] = LD8(BT + (h*64 + wcl + j*16 + q)*256 + kk + 8*g);
    #pragma unroll
    for (int i=0;i<2;i++)
      #pragma unroll
      for (int j=0;j<2;j++) acc[i][j] = MFMA(af[i], bfr[j], acc[i][j]);
  }
  #pragma unroll
  for (int i=0;i<2;i++)
    #pragma unroll
    for (int j=0;j<2;j++)
      #pragma unroll
      for (int r=0;r<4;r++){
        const int row = rb*64 + wr + i*16 + g*4 + r;
        const int col = h*64 + wcl + j*16 + q;
        const float gv = b2f(ws[WS_GG + row*1024 + col]);
        ws[WS_U2 + row*1024 + col] = f2b(acc[i][j][r] * gv);
      }
}

// ---------------- k_dh: dh = u1@Wo + u2@Wgo ; X = node_repr + dh (f32) ----------------
__global__ __launch_bounds__(256) void k_dh(const float* __restrict__ node_repr, u16* __restrict__ ws){
  const int t=threadIdx.x, lid=t&63, w=t>>6, g=lid>>4, q=lid&15;
  const int rb=blockIdx.x, cb=blockIdx.y*64;
  const int wr=(w>>1)*32, wcl=(w&1)*32;
  float* Xf = (float*)(ws + WS_X);
  f32x4 acc[2][2] = {};
  for (int kk=0;kk<256;kk+=32){
    s16x8 af[2], bfr[2];
    #pragma unroll
    for (int i=0;i<2;i++) af[i] = LD8(ws + WS_U1 + (rb*64 + wr + i*16 + q)*256 + kk + 8*g);
    #pragma unroll
    for (int j=0;j<2;j++) bfr[j] = LD8(ws + WS_WoT + (cb + wcl + j*16 + q)*256 + kk + 8*g);
    #pragma unroll
    for (int i=0;i<2;i++)
      #pragma unroll
      for (int j=0;j<2;j++) acc[i][j] = MFMA(af[i], bfr[j], acc[i][j]);
  }
  for (int kk=0;kk<1024;kk+=32){
    s16x8 af[2], bfr[2];
    #pragma unroll
    for (int i=0;i<2;i++) af[i] = LD8(ws + WS_U2 + (rb*64 + wr + i*16 + q)*1024 + kk + 8*g);
    #pragma unroll
    for (int j=0;j<2;j++) bfr[j] = LD8(ws + WS_WgoT + (cb + wcl + j*16 + q)*1024 + kk + 8*g);
    #pragma unroll
    for (int i=0;i<2;i++)
      #pragma unroll
      for (int j=0;j<2;j++) acc[i][j] = MFMA(af[i], bfr[j], acc[i][j]);
  }
  #pragma unroll
  for (int i=0;i<2;i++)
    #pragma unroll
    for (int j=0;j<2;j++)
      #pragma unroll
      for (int r=0;r<4;r++){
        const int row = rb*64 + wr + i*16 + g*4 + r;
        const int col = cb + wcl + j*16 + q;
        Xf[row*512 + col] = acc[i][j][r] + node_repr[row*512 + col];
      }
}

// ---------------- k_ln512: Y = LN(X)*g + b (bf16 out) ----------------
__global__ __launch_bounds__(256) void k_ln512(const float* __restrict__ g_, const float* __restrict__ b_,
                                               u16* __restrict__ ws){
  const int t=threadIdx.x, wid=t>>6, lane=t&63;
  const int row = blockIdx.x*4 + wid;
  const float* xr = (const float*)(ws + WS_X) + row*512;
  f32x8 xv = *(const f32x8*)(xr + lane*8);
  float s=0.f, s2=0.f;
  #pragma unroll
  for (int i=0;i<8;i++){ s+=xv[i]; s2+=xv[i]*xv[i]; }
  #pragma unroll
  for (int m=1;m<64;m<<=1){ s += __shfl_xor(s,m,64); s2 += __shfl_xor(s2,m,64); }
  const float mean = s*(1.f/512.f);
  const float var  = s2*(1.f/512.f) - mean*mean;
  const float rstd = rsqrtf(var + 1e-5f);
  u16x8 yv;
  #pragma unroll
  for (int i=0;i<8;i++) yv[i] = f2b((xv[i]-mean)*rstd*g_[lane*8+i] + b_[lane*8+i]);
  *(u16x8*)(ws + WS_Y + row*512 + lane*8) = yv;
}

// ---------------- k_nmlp1: H2 = gelu(Y @ nW1 + nb1) ; col-slab, double-buffered T3-lite ----------------
__global__ __launch_bounds__(256) void k_nmlp1(const u16* __restrict__ A,
                                               const u16* __restrict__ BT,
                                               const float* __restrict__ b1,
                                               u16* __restrict__ H){
  __shared__ alignas(16) u16 SH2[16384];
  const int t=threadIdx.x, lid=t&63, w=t>>6, g=lid>>4, q=lid&15;
  const int r0 = blockIdx.x*128, n0 = blockIdx.y*128;
  const int wc3 = w*32;
  f32x4 acc[8][2] = {};
  #pragma unroll
  for (int j=0;j<2;j++){
    const int v = t + 256*j;
    const int row = v>>2, sg = (v&3)*8;
    gload16(A  + (r0+row)*512 + sg, SH2 + (w*64 + 256*j)*8);
    gload16(BT + (n0+row)*512 + sg, SH2 + 4096 + (w*64 + 256*j)*8);
  }
  __syncthreads();
  for (int ks=0; ks<16; ++ks){
    const int cur = ks & 1;
    if (ks < 15){
      const int kk = (ks+1)*32;
      const int nb = cur ^ 1;
      #pragma unroll
      for (int j=0;j<2;j++){
        const int v = t + 256*j;
        const int row = v>>2, sg = (v&3)*8;
        gload16(A  + (r0+row)*512 + kk + sg, SH2 + nb*8192 + (w*64 + 256*j)*8);
        gload16(BT + (n0+row)*512 + kk + sg, SH2 + nb*8192 + 4096 + (w*64 + 256*j)*8);
      }
    }
    const u16* As = SH2 + cur*8192;
    const u16* Bs = As + 4096;
    s16x8 bf_[2];
    #pragma unroll
    for (int j=0;j<2;j++) bf_[j] = *(const s16x8*)(Bs + (wc3 + j*16 + q)*32 + g*8);
    #pragma unroll
    for (int i=0;i<8;i++){
      s16x8 af = *(const s16x8*)(As + (i*16+q)*32 + g*8);
      #pragma unroll
      for (int j=0;j<2;j++) acc[i][j] = MFMA(af, bf_[j], acc[i][j]);
    }
    __syncthreads();
  }
  #pragma unroll
  for (int p=0;p<2;p++){
    __syncthreads();
    #pragma unroll
    for (int i2=0;i2<4;i2++)
      #pragma unroll
      for (int j=0;j<2;j++)
        #pragma unroll
        for (int r=0;r<4;r++){
          const int rl = i2*16 + g*4 + r;
          const int cl = wc3 + j*16 + q;
          SH2[rl*136 + cl] = f2b(gelu_fast(acc[p*4+i2][j][r] + b1[n0 + cl]));
        }
    __syncthreads();
    #pragma unroll
    for (int it=0; it<4; ++it){
      const int v = t + 256*it;
      const int rrow = v >> 4, sc = (v & 15)*8;
      *(u16x8*)(H + (r0 + p*64 + rrow)*2048 + n0 + sc) = *(const u16x8*)(SH2 + rrow*136 + sc);
    }
  }
}

// ---------------- k_nmlp2: out = X + H2 @ nW2 + nb2 ; 64x64 tile ----------------
__global__ __launch_bounds__(256) void k_nmlp2(const u16* __restrict__ A,
                                               const u16* __restrict__ BT,
                                               const float* __restrict__ b2,
                                               const float* __restrict__ Xf,
                                               float* __restrict__ out){
  __shared__ alignas(16) u16 As[64*32];
  __shared__ alignas(16) u16 Bs[64*32];
  const int t=threadIdx.x, lid=t&63, w=t>>6, g=lid>>4, q=lid&15;
  const int r0 = blockIdx.x*64, n0 = blockIdx.y*64;
  const int wr=(w>>1)*32, wc2=(w&1)*32;
  f32x4 acc[2][2] = {};
  for (int kk=0;kk<2048;kk+=32){
    __syncthreads();
    {
      const int row = t>>2, sg = (t&3)*8;
      gload16(A  + (r0+row)*2048 + kk + sg, As + (w*64)*8);
      gload16(BT + (n0+row)*2048 + kk + sg, Bs + (w*64)*8);
    }
    __syncthreads();
    s16x8 af[2], bf_[2];
    #pragma unroll
    for (int i=0;i<2;i++) af[i]  = *(const s16x8*)(As + (wr+i*16+q)*32 + g*8);
    #pragma unroll
    for (int j=0;j<2;j++) bf_[j] = *(const s16x8*)(Bs + (wc2+j*16+q)*32 + g*8);
    #pragma unroll
    for (int i=0;i<2;i++)
      #pragma unroll
      for (int j=0;j<2;j++) acc[i][j] = MFMA(af[i], bf_[j], acc[i][j]);
  }
  #pragma unroll
  for (int i=0;i<2;i++)
    #pragma unroll
    for (int j=0;j<2;j++)
      #pragma unroll
      for (int r=0;r<4;r++){
        const int row = r0 + wr + i*16 + g*4 + r;
        const int col = n0 + wc2 + j*16 + q;
        out[row*512 + col] = acc[i][j][r] + b2[col] + Xf[row*512 + col];
      }
}

extern "C" void kernel_launch(void* const* d_in, const int* in_sizes, int n_in,
                              void* d_out, int out_size, void* d_ws, size_t ws_size,
                              hipStream_t stream){
  (void)in_sizes; (void)n_in; (void)out_size; (void)ws_size;
  const float* node_repr = (const float*)d_in[0];
  const float* edge_repr = (const float*)d_in[1];
  const int* edge_index = (const int*)d_in[2];
  const int* edge_mask  = (const int*)d_in[3];
  const float* mask_bw = (const float*)d_in[4];
  u16* ws = (u16*)d_ws;

  P13 ps;
  const int srcIdx[13] = {5,10,12,17,19,16,22,25,27,6,7,14,20};
  for (int i=0;i<13;i++) ps.p[i] = (const float*)d_in[srcIdx[i]];

  hipLaunchKernelGGL(k_transpose, dim3(1120), dim3(256), 0, stream, ps, ws);
  hipLaunchKernelGGL(k_cvtnode, dim3(512), dim3(256), 0, stream, node_repr, ws + WS_H);
  hipLaunchKernelGGL(k_proj, dim3(32,28), dim3(256), 0, stream,
                     (const float*)d_in[15], (const float*)d_in[21], ws);
  hipLaunchKernelGGL(k_edgepre, dim3(1024), dim3(512), 0, stream,
                     edge_repr, edge_index, mask_bw,
                     (const float*)d_in[8], (const float*)d_in[9], ws);
  for (int grp=0; grp<2; ++grp){
    const u16* Ag = ws + WS_YE + grp*32768*256;
    u16* Hg = ws + WS_H;
    u16* msgg = ws + WS_MSG + grp*32768*256;
    const int* emg = edge_mask + grp*32768;
    hipLaunchKernelGGL(k_mlp1, dim3(256,8), dim3(256), 0, stream,
                       Ag, ws + WS_W1T, (const float*)d_in[11], Hg);
    hipLaunchKernelGGL(k_mlp2, dim3(256,2), dim3(256), 0, stream,
                       Hg, ws + WS_W2T, (const float*)d_in[13], emg, msgg);
  }
  // attention path: Tm GEMM -> ab GEMM -> light per-node kernel
  hipLaunchKernelGGL(k_tm, dim3(512,2), dim3(256), 0, stream,
                     ws + WS_MSG, ws + WS_WmT, ws + WS_H);
  hipLaunchKernelGGL(k_ab, dim3(512), dim3(256), 0, stream,
                     ws + WS_H, (const float*)d_in[18], (float*)(ws + WS_YE));
  hipLaunchKernelGGL(k_attn2, dim3(2048), dim3(256), 0, stream,
                     edge_mask, ws);
  hipLaunchKernelGGL(k_og, dim3(32,16), dim3(256), 0, stream, ws);
  hipLaunchKernelGGL(k_dh, dim3(32,8), dim3(256), 0, stream, node_repr, ws);
  hipLaunchKernelGGL(k_ln512, dim3(512), dim3(256), 0, stream,
                     (const float*)d_in[23], (const float*)d_in[24], ws);
  hipLaunchKernelGGL(k_nmlp1, dim3(16,16), dim3(256), 0, stream,
                     ws + WS_Y, ws + WS_nW1T, (const float*)d_in[26], ws + WS_H);
  hipLaunchKernelGGL(k_nmlp2, dim3(32,8), dim3(256), 0, stream,
                     ws + WS_H, ws + WS_nW2T, (const float*)d_in[28],
                     (const float*)(ws + WS_X), (float*)d_out);
}

// Round 22
// 343.916 us; speedup vs baseline: 1.0178x; 1.0178x over previous
//
#include <hip/hip_runtime.h>
#include <hip/hip_bf16.h>

typedef unsigned short u16;
typedef short s16x8 __attribute__((ext_vector_type(8)));
typedef float f32x4 __attribute__((ext_vector_type(4)));
typedef float f32x8 __attribute__((ext_vector_type(8)));
typedef u16 u16x8 __attribute__((ext_vector_type(8)));

#define DEV static __device__ __forceinline__

DEV float b2f(u16 u){ unsigned int i=((unsigned int)u)<<16; float f; __builtin_memcpy(&f,&i,4); return f; }
DEV u16 f2b(float x){ __hip_bfloat16 h=__float2bfloat16(x); u16 u; __builtin_memcpy(&u,&h,2); return u; }
DEV f32x4 MFMA(s16x8 a, s16x8 b, f32x4 c){ return __builtin_amdgcn_mfma_f32_16x16x32_bf16(a,b,c,0,0,0); }
DEV s16x8 LD8(const u16* p){ return *(const s16x8*)p; }
// sigmoid-form gelu: x*sigmoid(1.702x). |dev from erf-gelu| <= 0.005 for |x|<1.5
DEV float gelu_fast(float x){
  return x / (1.f + __expf(-1.702f*x));
}
DEV float sigmf(float x){ return 1.0f/(1.0f+__expf(-x)); }

// async global->LDS, 16B per lane. LDS dest must be wave-uniform base (HW adds lane*16).
DEV void gload16(const u16* g, u16* l){
  __builtin_amdgcn_global_load_lds((const __attribute__((address_space(1))) void*)g,
                                   (__attribute__((address_space(3))) void*)l, 16, 0, 0);
}

// ---------------- workspace layout (u16 elements) ----------------
#define WS_WeT   0
#define WS_W1T   65536
#define WS_W2T   327680
#define WS_WmT   589824
#define WS_WvT   655360
#define WS_WoT   917504
#define WS_WgoT  1048576
#define WS_nW1T  1572864
#define WS_nW2T  2621440
#define WS_SrcT  3670016
#define WS_TgtT  3801088
#define WS_GateT 3932160
#define WS_GgT   4063232
#define WS_NM    4587520
#define WS_TGT   5111808
#define WS_GP    5636096
#define WS_GG    6160384
#define WS_MSG   8257536
// U2 / X / Y alias the MSG region (MSG dead after k_attn2)
#define WS_U2    8257536
#define WS_X     10354688   /* f32 region: 1,048,576 floats */
#define WS_Y     12451840
#define WS_WM    25034752
#define WS_U1    33423360
#define WS_YE    33947648   /* edge-LN Y; later AB f32 [65536][16] */
#define WS_H     50724864   /* node bf16 (early); edge-MLP hidden; Tm; node-MLP H2 */
// total 84,279,296 u16 = 168.6 MB

// ---------------- transpose + bf16-cast all weights ----------------
struct P13 { const float* p[13]; };
__device__ const int TR_START[14] = {0,16,80,144,160,224,256,384,640,896,928,960,992,1120};
__device__ const int TR_R[13]   = {256,256,1024,256,256,256,1024,512,2048,512,512,512,512};
__device__ const int TR_C[13]   = {256,1024,256,256,1024,512,512,2048,512,256,256,256,1024};
__device__ const int TR_DST[13] = {WS_WeT,WS_W1T,WS_W2T,WS_WmT,WS_WvT,WS_WoT,WS_WgoT,
                                   WS_nW1T,WS_nW2T,WS_SrcT,WS_TgtT,WS_GateT,WS_GgT};

__global__ __launch_bounds__(256) void k_transpose(P13 ps, u16* __restrict__ ws){
  __shared__ alignas(16) u16 Ts[64][72];
  const int t = threadIdx.x;
  int bid = blockIdx.x;
  int mi = 0;
  #pragma unroll 1
  while (bid >= TR_START[mi+1]) ++mi;
  const float* src = ps.p[mi];
  const int R = TR_R[mi], C = TR_C[mi];
  u16* dst = ws + TR_DST[mi];
  const int ti = bid - TR_START[mi];
  const int tcn = C >> 6;
  const int tr = ti / tcn, tc = ti % tcn;
  {
    const int row = t >> 2, cs = (t & 3) * 16;
    const float* sp = src + (tr*64 + row)*C + tc*64 + cs;
    u16x8 a, b;
    #pragma unroll
    for (int i=0;i<8;i++){ a[i]=f2b(sp[i]); b[i]=f2b(sp[8+i]); }
    *(u16x8*)&Ts[row][cs]   = a;
    *(u16x8*)&Ts[row][cs+8] = b;
  }
  __syncthreads();
  {
    const int col = t >> 2, rs = (t & 3) * 16;
    u16x8 a, b;
    #pragma unroll
    for (int i=0;i<8;i++){ a[i]=Ts[rs+i][col]; b[i]=Ts[rs+8+i][col]; }
    u16* dp = dst + (tc*64 + col)*R + tr*64 + rs;
    *(u16x8*)dp = a;
    *(u16x8*)(dp+8) = b;
  }
}

// ---------------- k_cvtnode: node_repr f32 -> bf16 (into WS_H, used by k_proj only) ----------------
__global__ __launch_bounds__(256) void k_cvtnode(const float* __restrict__ src, u16* __restrict__ dst){
  const int i = (blockIdx.x*256 + threadIdx.x)*8;
  f32x8 v = *(const f32x8*)(src + i);
  u16x8 o;
  #pragma unroll
  for (int j=0;j<8;j++) o[j] = f2b(v[j]);
  *(u16x8*)(dst + i) = o;
}

// ---------------- k_proj: node projections + gates (A from bf16 node) ----------------
__global__ __launch_bounds__(256) void k_proj(const float* __restrict__ bgate,
                                              const float* __restrict__ bgg,
                                              u16* __restrict__ ws){
  const int t=threadIdx.x, lid=t&63, w=t>>6, g=lid>>4, q=lid&15;
  const int rb = blockIdx.x, yb = blockIdx.y;
  const u16* nb = ws + WS_H;   // node bf16 [2048][512]
  const u16* BT; u16* dst; int Nseg, colbase, act=0; const float* bias=nullptr;
  if (yb < 4){ BT=ws+WS_SrcT;  dst=ws+WS_NM; Nseg=256;  colbase=yb*64; }
  else if (yb < 8){ BT=ws+WS_TgtT;  dst=ws+WS_TGT; Nseg=256; colbase=(yb-4)*64; }
  else if (yb < 12){ BT=ws+WS_GateT; dst=ws+WS_GP; Nseg=256; colbase=(yb-8)*64; act=1; bias=bgate; }
  else { BT=ws+WS_GgT; dst=ws+WS_GG; Nseg=1024; colbase=(yb-12)*64; act=1; bias=bgg; }
  const int wr=(w>>1)*32, wcl=(w&1)*32;
  f32x4 acc[2][2] = {};
  for (int kk=0; kk<512; kk+=32){
    s16x8 af[2], bfr[2];
    #pragma unroll
    for (int i=0;i<2;i++) af[i] = LD8(nb + (rb*64 + wr + i*16 + q)*512 + kk + 8*g);
    #pragma unroll
    for (int j=0;j<2;j++) bfr[j] = LD8(BT + (colbase + wcl + j*16 + q)*512 + kk + 8*g);
    #pragma unroll
    for (int i=0;i<2;i++)
      #pragma unroll
      for (int j=0;j<2;j++) acc[i][j] = MFMA(af[i], bfr[j], acc[i][j]);
  }
  #pragma unroll
  for (int i=0;i<2;i++)
    #pragma unroll
    for (int j=0;j<2;j++)
      #pragma unroll
      for (int r=0;r<4;r++){
        const int row = rb*64 + wr + i*16 + g*4 + r;
        const int col = wcl + j*16 + q;
        float v = acc[i][j][r];
        if (act) v = sigmf(v + bias[colbase+col]);
        dst[row*Nseg + colbase + col] = f2b(v);
      }
}

// ---------------- k_edgepre: 512-thread (8-wave), acc[2][4]=32 VGPR/thread ----------------
#define GB_S 528
__global__ __launch_bounds__(512) void k_edgepre(
    const float* __restrict__ edge_repr, const int* __restrict__ edge_index,
    const float* __restrict__ mask_bw,
    const float* __restrict__ ln_g, const float* __restrict__ ln_b,
    u16* __restrict__ ws)
{
  __shared__ alignas(16) char SH[64*GB_S];   // Gb (gather) / As+Bs (GEMM) / Ye stage
  __shared__ float rsS[4][64], rsQ[4][64];
  __shared__ int idxL[64]; __shared__ float mbwL[64];

  const int t=threadIdx.x, lid=t&63, w=t>>6, g=lid>>4, q=lid&15;
  const int R0 = blockIdx.x * 64;
  const int wrg = (w>>2)*32;       // row group: 0 or 32
  const int wcl = (w&3)*64;        // col group: 0,64,128,192
  u16* As = (u16*)SH;            // [64][32]
  u16* Bs = (u16*)(SH + 4096);   // [256][32]

  if (t < 64){
    idxL[t] = edge_index[R0+t];
    mbwL[t] = mask_bw[R0+t];
  }
  __syncthreads();

  const u16* nm = ws + WS_NM;
  const u16* tg = ws + WS_TGT;
  // vectorized gather staging into SH (as Gb): 2048 segs / 512 threads = 4 iters
  #pragma unroll
  for (int it=0; it<4; ++it){
    const int v = t + 512*it;
    const int row = v >> 5;
    const int sc  = (v & 31) * 8;
    const int er  = R0 + row;
    const int gnd = er >> 5;
    const int bi  = gnd >> 10;
    const int srow = bi*1024 + idxL[row];
    const float mb = mbwL[row];
    u16x8 nv = *(const u16x8*)(nm + srow*256 + sc);
    u16x8 tv = *(const u16x8*)(tg + gnd*256 + sc);
    u16x8 ov;
    #pragma unroll
    for (int j2=0;j2<8;j2++) ov[j2] = f2b(b2f(nv[j2])*mb + b2f(tv[j2]));
    *(u16x8*)(SH + row*GB_S + 2*sc) = ov;
  }
  __syncthreads();
  // acc init from staged gather; Gb dead afterwards
  f32x4 acc[2][4];
  #pragma unroll
  for (int i=0;i<2;i++)
    #pragma unroll
    for (int r=0;r<4;r++){
      const int row = wrg + i*16 + g*4 + r;
      #pragma unroll
      for (int j=0;j<4;j++){
        const int col = wcl + j*16 + q;
        acc[i][j][r] = b2f(*(const u16*)(SH + row*GB_S + 2*col));
      }
    }
  // pre-GEMM (SH reused as As/Bs)
  for (int kk=0; kk<256; kk+=32){
    __syncthreads();
    if (t < 256){
      const int row = t >> 2, c0 = (t & 3) * 8;
      const float* sp = edge_repr + (R0 + row)*256 + kk + c0;
      f32x8 fv = *(const f32x8*)sp;
      u16x8 av;
      #pragma unroll
      for (int j2=0;j2<8;j2++) av[j2] = f2b(fv[j2]);
      *(u16x8*)(As + row*32 + c0) = av;
    }
    #pragma unroll
    for (int j=0;j<2;j++){
      const int s = t + 512*j;
      const int brow = s >> 2, ko = (s & 3) * 8;
      u16* ldsB = Bs + (512*j + w*64)*8;
      gload16(ws + WS_WeT + brow*256 + kk + ko, ldsB);
    }
    __syncthreads();
    s16x8 af[2], bfr[4];
    #pragma unroll
    for (int i=0;i<2;i++) af[i]  = *(const s16x8*)(As + (wrg + i*16 + q)*32 + g*8);
    #pragma unroll
    for (int j=0;j<4;j++) bfr[j] = *(const s16x8*)(Bs + (wcl + j*16 + q)*32 + g*8);
    #pragma unroll
    for (int i=0;i<2;i++)
      #pragma unroll
      for (int j=0;j<4;j++) acc[i][j] = MFMA(af[i], bfr[j], acc[i][j]);
  }
  // LayerNorm over 256 (4 col-waves share each row group)
  #pragma unroll
  for (int i=0;i<2;i++)
    #pragma unroll
    for (int r=0;r<4;r++){
      float s=0.f, s2=0.f;
      #pragma unroll
      for (int j=0;j<4;j++){ float v=acc[i][j][r]; s+=v; s2+=v*v; }
      #pragma unroll
      for (int m=1;m<16;m<<=1){ s += __shfl_xor(s,m,64); s2 += __shfl_xor(s2,m,64); }
      if (q==0){ const int row=wrg+i*16+g*4+r; rsS[w&3][row]=s; rsQ[w&3][row]=s2; }
    }
  __syncthreads();   // As/Bs reads done -> SH free for Ye staging
  // LN values staged into SH (Gb layout), then coalesced copy-out
  #pragma unroll
  for (int i=0;i<2;i++)
    #pragma unroll
    for (int r=0;r<4;r++){
      const int row = wrg + i*16 + g*4 + r;
      const float s  = rsS[0][row]+rsS[1][row]+rsS[2][row]+rsS[3][row];
      const float s2 = rsQ[0][row]+rsQ[1][row]+rsQ[2][row]+rsQ[3][row];
      const float mean = s*(1.f/256.f);
      const float var  = s2*(1.f/256.f) - mean*mean;
      const float rstd = rsqrtf(var + 1e-5f);
      #pragma unroll
      for (int j=0;j<4;j++){
        const int col = wcl + j*16 + q;
        *(u16*)(SH + row*GB_S + 2*col) = f2b((acc[i][j][r]-mean)*rstd*ln_g[col] + ln_b[col]);
      }
    }
  __syncthreads();
  u16* Ye = ws + WS_YE;
  #pragma unroll
  for (int it=0; it<4; ++it){
    const int v = t + 512*it;
    const int row = v >> 5, sc = (v & 31)*8;
    *(u16x8*)(Ye + (R0+row)*256 + sc) = *(const u16x8*)(SH + row*GB_S + 2*sc);
  }
}

// ---------------- k_mlp1: H = gelu(Y @ W1 + b1) ; col-slab, double-buffered T3-lite ----------------
__global__ __launch_bounds__(256) void k_mlp1(const u16* __restrict__ A,
                                              const u16* __restrict__ BT,
                                              const float* __restrict__ b1,
                                              u16* __restrict__ H){
  __shared__ alignas(16) u16 SH2[16384];   // 32KB: 2x(As[128][32]+Bs[128][32]); epilogue reuses [0..8704)
  const int t=threadIdx.x, lid=t&63, w=t>>6, g=lid>>4, q=lid&15;
  const int r0 = blockIdx.x*128, n0 = blockIdx.y*128;
  const int wc3 = w*32;
  f32x4 acc[8][2] = {};
  // prologue: stage buffer 0 with kk=0
  #pragma unroll
  for (int j=0;j<2;j++){
    const int v = t + 256*j;
    const int row = v>>2, sg = (v&3)*8;
    gload16(A  + (r0+row)*256 + sg,        SH2 + (w*64 + 256*j)*8);
    gload16(BT + (n0+row)*256 + sg,        SH2 + 4096 + (w*64 + 256*j)*8);
  }
  __syncthreads();
  for (int ks=0; ks<8; ++ks){
    const int cur = ks & 1;
    if (ks < 7){
      const int kk = (ks+1)*32;
      const int nb = cur ^ 1;
      #pragma unroll
      for (int j=0;j<2;j++){
        const int v = t + 256*j;
        const int row = v>>2, sg = (v&3)*8;
        gload16(A  + (r0+row)*256 + kk + sg, SH2 + nb*8192 + (w*64 + 256*j)*8);
        gload16(BT + (n0+row)*256 + kk + sg, SH2 + nb*8192 + 4096 + (w*64 + 256*j)*8);
      }
    }
    const u16* As = SH2 + cur*8192;
    const u16* Bs = As + 4096;
    s16x8 bf_[2];
    #pragma unroll
    for (int j=0;j<2;j++) bf_[j] = *(const s16x8*)(Bs + (wc3 + j*16 + q)*32 + g*8);
    #pragma unroll
    for (int i=0;i<8;i++){
      s16x8 af = *(const s16x8*)(As + (i*16+q)*32 + g*8);
      #pragma unroll
      for (int j=0;j<2;j++) acc[i][j] = MFMA(af, bf_[j], acc[i][j]);
    }
    __syncthreads();   // drains next-tile gloads; frees cur for ks+2
  }
  // staged epilogue: 2 passes of 64 rows through SH2[0..64*136)
  #pragma unroll
  for (int p=0;p<2;p++){
    __syncthreads();
    #pragma unroll
    for (int i2=0;i2<4;i2++)
      #pragma unroll
      for (int j=0;j<2;j++)
        #pragma unroll
        for (int r=0;r<4;r++){
          const int rl = i2*16 + g*4 + r;
          const int cl = wc3 + j*16 + q;
          SH2[rl*136 + cl] = f2b(gelu_fast(acc[p*4+i2][j][r] + b1[n0 + cl]));
        }
    __syncthreads();
    #pragma unroll
    for (int it=0; it<4; ++it){
      const int v = t + 256*it;
      const int rrow = v >> 4, sc = (v & 15)*8;
      *(u16x8*)(H + (r0 + p*64 + rrow)*1024 + n0 + sc) = *(const u16x8*)(SH2 + rrow*136 + sc);
    }
  }
}

// ---------------- k_mlp2: msg = mask * (H @ W2 + b2) ; 128x128 tile, direct store ----------------
__global__ __launch_bounds__(256) void k_mlp2(const u16* __restrict__ A,
                                              const u16* __restrict__ BT,
                                              const float* __restrict__ b2,
                                              const int* __restrict__ em,
                                              u16* __restrict__ msg){
  __shared__ alignas(16) u16 As[128*32];
  __shared__ alignas(16) u16 Bs[128*32];
  __shared__ int emL[128];
  const int t=threadIdx.x, lid=t&63, w=t>>6, g=lid>>4, q=lid&15;
  const int r0 = blockIdx.x*128, n0 = blockIdx.y*128;
  const int wr=(w>>1)*64, wc2=(w&1)*64;
  if (t < 128) emL[t] = em[r0 + t];
  f32x4 acc[4][4] = {};
  for (int kk=0;kk<1024;kk+=32){
    __syncthreads();
    #pragma unroll
    for (int j=0;j<2;j++){
      const int v = t + 256*j;
      const int row = v>>2, sg = (v&3)*8;
      gload16(A  + (r0+row)*1024 + kk + sg, As + (w*64 + 256*j)*8);
      gload16(BT + (n0+row)*1024 + kk + sg, Bs + (w*64 + 256*j)*8);
    }
    __syncthreads();
    s16x8 af[4], bf_[4];
    #pragma unroll
    for (int i=0;i<4;i++) af[i]  = *(const s16x8*)(As + (wr+i*16+q)*32 + g*8);
    #pragma unroll
    for (int j=0;j<4;j++) bf_[j] = *(const s16x8*)(Bs + (wc2+j*16+q)*32 + g*8);
    #pragma unroll
    for (int i=0;i<4;i++)
      #pragma unroll
      for (int j=0;j<4;j++) acc[i][j] = MFMA(af[i], bf_[j], acc[i][j]);
  }
  #pragma unroll
  for (int i=0;i<4;i++)
    #pragma unroll
    for (int j=0;j<4;j++)
      #pragma unroll
      for (int r=0;r<4;r++){
        const int rl  = wr + i*16 + g*4 + r;
        const int col = n0 + wc2 + j*16 + q;
        float v = acc[i][j][r] + b2[col];
        if (!emL[rl]) v = 0.f;
        msg[(r0+rl)*256 + col] = f2b(v);
      }
}

// ---------------- k_tm: Tm = lrelu(msg @ Wm) ; col-slab, double-buffered T3-lite ----------------
__global__ __launch_bounds__(256) void k_tm(const u16* __restrict__ A,
                                            const u16* __restrict__ BT,
                                            u16* __restrict__ Tm){
  __shared__ alignas(16) u16 SH2[16384];
  const int t=threadIdx.x, lid=t&63, w=t>>6, g=lid>>4, q=lid&15;
  const int r0 = blockIdx.x*128, n0 = blockIdx.y*128;
  const int wc3 = w*32;
  f32x4 acc[8][2] = {};
  #pragma unroll
  for (int j=0;j<2;j++){
    const int v = t + 256*j;
    const int row = v>>2, sg = (v&3)*8;
    gload16(A  + (r0+row)*256 + sg, SH2 + (w*64 + 256*j)*8);
    gload16(BT + (n0+row)*256 + sg, SH2 + 4096 + (w*64 + 256*j)*8);
  }
  __syncthreads();
  for (int ks=0; ks<8; ++ks){
    const int cur = ks & 1;
    if (ks < 7){
      const int kk = (ks+1)*32;
      const int nb = cur ^ 1;
      #pragma unroll
      for (int j=0;j<2;j++){
        const int v = t + 256*j;
        const int row = v>>2, sg = (v&3)*8;
        gload16(A  + (r0+row)*256 + kk + sg, SH2 + nb*8192 + (w*64 + 256*j)*8);
        gload16(BT + (n0+row)*256 + kk + sg, SH2 + nb*8192 + 4096 + (w*64 + 256*j)*8);
      }
    }
    const u16* As = SH2 + cur*8192;
    const u16* Bs = As + 4096;
    s16x8 bf_[2];
    #pragma unroll
    for (int j=0;j<2;j++) bf_[j] = *(const s16x8*)(Bs + (wc3 + j*16 + q)*32 + g*8);
    #pragma unroll
    for (int i=0;i<8;i++){
      s16x8 af = *(const s16x8*)(As + (i*16+q)*32 + g*8);
      #pragma unroll
      for (int j=0;j<2;j++) acc[i][j] = MFMA(af, bf_[j], acc[i][j]);
    }
    __syncthreads();
  }
  #pragma unroll
  for (int p=0;p<2;p++){
    __syncthreads();
    #pragma unroll
    for (int i2=0;i2<4;i2++)
      #pragma unroll
      for (int j=0;j<2;j++)
        #pragma unroll
        for (int r=0;r<4;r++){
          const int rl = i2*16 + g*4 + r;
          const int cl = wc3 + j*16 + q;
          float v = acc[p*4+i2][j][r];
          SH2[rl*136 + cl] = f2b(v > 0.f ? v : 0.01f*v);
        }
    __syncthreads();
    #pragma unroll
    for (int it=0; it<4; ++it){
      const int v = t + 256*it;
      const int rrow = v >> 4, sc = (v & 15)*8;
      *(u16x8*)(Tm + (r0 + p*64 + rrow)*256 + n0 + sc) = *(const u16x8*)(SH2 + rrow*136 + sc);
    }
  }
}

// ---------------- k_ab: AB = Tm @ Wab ; 128-row x 16-col tiles ----------------
__global__ __launch_bounds__(256) void k_ab(const u16* __restrict__ A,
                                            const float* __restrict__ Wab,
                                            float* __restrict__ AB){
  __shared__ alignas(16) u16 As[128*32];
  __shared__ alignas(16) char WbT[16*528];
  const int t=threadIdx.x, lid=t&63, w=t>>6, g=lid>>4, q=lid&15;
  const int r0 = blockIdx.x*128;
  {
    const float* wr_ = Wab + t*16;
    #pragma unroll
    for (int h=0;h<16;h++) *(u16*)(WbT + h*528 + 2*t) = f2b(wr_[h]);
  }
  f32x4 acc[2] = {};
  for (int kk=0;kk<256;kk+=32){
    __syncthreads();
    #pragma unroll
    for (int j=0;j<2;j++){
      const int s = t + 256*j;
      const int row = s>>2, ko = (s&3)*8;
      gload16(A + (r0+row)*256 + kk + ko, As + (w*64 + 256*j)*8);
    }
    __syncthreads();
    s16x8 bf_ = *(const s16x8*)(WbT + q*528 + 2*(kk + 8*g));
    #pragma unroll
    for (int i=0;i<2;i++){
      s16x8 af = *(const s16x8*)(As + (w*32 + i*16 + q)*32 + g*8);
      acc[i] = MFMA(af, bf_, acc[i]);
    }
  }
  #pragma unroll
  for (int i=0;i<2;i++)
    #pragma unroll
    for (int r=0;r<4;r++){
      const int row = r0 + w*32 + i*16 + g*4 + r;
      AB[row*16 + q] = acc[i][r];
    }
}

// ---------------- k_attn2: per-node softmax + wm + pool (light) ----------------
#define AM_S 528
#define MT_S 80
__global__ __launch_bounds__(256) void k_attn2(const int* __restrict__ edge_mask,
                                               u16* __restrict__ ws){
  __shared__ alignas(16) char Am[32*AM_S];
  __shared__ alignas(16) char Mt[256*MT_S];
  __shared__ alignas(16) char Pb[16*80];
  __shared__ float Pp[32][16];
  __shared__ int emL[32];
  __shared__ float cntS;

  const int t=threadIdx.x, lid=t&63, w=t>>6, g=lid>>4, q=lid&15;
  const int nd = blockIdx.x;
  const int wc = w*64;
  const u16* msg = ws + WS_MSG + nd*32*256;
  const float* ab = (const float*)(ws + WS_YE) + nd*32*16;

  if (t < 32) emL[t] = edge_mask[nd*32 + t];
  #pragma unroll
  for (int it=0; it<4; ++it){
    const int v = t + 256*it;
    const int row = v >> 5, sc = (v & 31)*8;
    u16x8 val = *(const u16x8*)(msg + row*256 + sc);
    *(u16x8*)(Am + row*AM_S + 2*sc) = val;
  }
  {
    const int k = t >> 4, h = t & 15;
    Pp[k][h]    = ab[k*16 + h];
    Pp[k+16][h] = ab[(k+16)*16 + h];
  }
  __syncthreads();
  if (t == 0){ float c=0.f; for (int k=0;k<32;k++) c += emL[k]?1.f:0.f; cntS=c; }
  {
    const int c = t;
    #pragma unroll 1
    for (int k=0;k<32;k++){
      u16 vv = *(const u16*)(Am + k*AM_S + 2*c);
      *(u16*)(Mt + c*MT_S + 2*k) = vv;
    }
  }
  if (t < 16){
    const int h = t;
    float m = -3.4028235e38f;
    float pv[32];
    for (int k=0;k<32;k++){ pv[k] = emL[k] ? Pp[k][h] : -3.4028235e38f; m = fmaxf(m, pv[k]); }
    float s = 0.f;
    float ev[32];
    for (int k=0;k<32;k++){ ev[k]=__expf(pv[k]-m); s+=ev[k]; }
    const float inv = 1.f/s;
    for (int k=0;k<32;k++) *(u16*)(Pb + h*80 + 2*k) = f2b(ev[k]*inv);
  }
  __syncthreads();
  {
    s16x8 pa = *(const s16x8*)(Pb + q*80 + 2*(8*g));
    f32x4 wmac[4] = {};
    #pragma unroll
    for (int j=0;j<4;j++){
      s16x8 mb = *(const s16x8*)(Mt + (wc + j*16 + q)*MT_S + 2*(8*g));
      wmac[j] = MFMA(pa, mb, wmac[j]);
    }
    u16* wmw = ws + WS_WM;
    #pragma unroll
    for (int j=0;j<4;j++)
      #pragma unroll
      for (int r=0;r<4;r++){
        const int hh = g*4 + r;
        const int col = wc + j*16 + q;
        wmw[hh*(2048*256) + nd*256 + col] = f2b(wmac[j][r]);
      }
  }
  {
    const int c = t;
    float s = 0.f;
    #pragma unroll 1
    for (int k=0;k<32;k++) s += b2f(*(const u16*)(Am + k*AM_S + 2*c));
    const float o = s / (cntS + 1e-6f);
    ws[WS_U1 + nd*256 + c] = f2b(o * b2f(ws[WS_GP + nd*256 + c]));
  }
}

// ---------------- k_og: per-head value GEMM + gate -> U2 ----------------
__global__ __launch_bounds__(256) void k_og(u16* __restrict__ ws){
  const int t=threadIdx.x, lid=t&63, w=t>>6, g=lid>>4, q=lid&15;
  const int rb=blockIdx.x, h=blockIdx.y;
  const int wr=(w>>1)*32, wcl=(w&1)*32;
  const u16* A  = ws + WS_WM  + h*(2048*256);
  const u16* BT = ws + WS_WvT;
  f32x4 acc[2][2] = {};
  for (int kk=0;kk<256;kk+=32){
    s16x8 af[2], bfr[2];
    #pragma unroll
    for (int i=0;i<2;i++) af[i] = LD8(A + (rb*64 + wr + i*16 + q)*256 + kk + 8*g);
    #pragma unroll
    for (int j=0;j<2;j++) bfr[j] = LD8(BT + (h*64 + wcl + j*16 + q)*256 + kk + 8*g);
    #pragma unroll
    for (int i=0;i<2;i++)
      #pragma unroll
      for (int j=0;j<2;j++) acc[i][j] = MFMA(af[i], bfr[j], acc[i][j]);
  }
  #pragma unroll
  for (int i=0;i<2;i++)
    #pragma unroll
    for (int j=0;j<2;j++)
      #pragma unroll
      for (int r=0;r<4;r++){
        const int row = rb*64 + wr + i*16 + g*4 + r;
        const int col = h*64 + wcl + j*16 + q;
        const float gv = b2f(ws[WS_GG + row*1024 + col]);
        ws[WS_U2 + row*1024 + col] = f2b(acc[i][j][r] * gv);
      }
}

// ---------------- k_dh: dh = u1@Wo + u2@Wgo ; X = node_repr + dh (f32) ----------------
__global__ __launch_bounds__(256) void k_dh(const float* __restrict__ node_repr, u16* __restrict__ ws){
  const int t=threadIdx.x, lid=t&63, w=t>>6, g=lid>>4, q=lid&15;
  const int rb=blockIdx.x, cb=blockIdx.y*64;
  const int wr=(w>>1)*32, wcl=(w&1)*32;
  float* Xf = (float*)(ws + WS_X);
  f32x4 acc[2][2] = {};
  for (int kk=0;kk<256;kk+=32){
    s16x8 af[2], bfr[2];
    #pragma unroll
    for (int i=0;i<2;i++) af[i] = LD8(ws + WS_U1 + (rb*64 + wr + i*16 + q)*256 + kk + 8*g);
    #pragma unroll
    for (int j=0;j<2;j++) bfr[j] = LD8(ws + WS_WoT + (cb + wcl + j*16 + q)*256 + kk + 8*g);
    #pragma unroll
    for (int i=0;i<2;i++)
      #pragma unroll
      for (int j=0;j<2;j++) acc[i][j] = MFMA(af[i], bfr[j], acc[i][j]);
  }
  for (int kk=0;kk<1024;kk+=32){
    s16x8 af[2], bfr[2];
    #pragma unroll
    for (int i=0;i<2;i++) af[i] = LD8(ws + WS_U2 + (rb*64 + wr + i*16 + q)*1024 + kk + 8*g);
    #pragma unroll
    for (int j=0;j<2;j++) bfr[j] = LD8(ws + WS_WgoT + (cb + wcl + j*16 + q)*1024 + kk + 8*g);
    #pragma unroll
    for (int i=0;i<2;i++)
      #pragma unroll
      for (int j=0;j<2;j++) acc[i][j] = MFMA(af[i], bfr[j], acc[i][j]);
  }
  #pragma unroll
  for (int i=0;i<2;i++)
    #pragma unroll
    for (int j=0;j<2;j++)
      #pragma unroll
      for (int r=0;r<4;r++){
        const int row = rb*64 + wr + i*16 + g*4 + r;
        const int col = cb + wcl + j*16 + q;
        Xf[row*512 + col] = acc[i][j][r] + node_repr[row*512 + col];
      }
}

// ---------------- k_ln512: Y = LN(X)*g + b (bf16 out) ----------------
__global__ __launch_bounds__(256) void k_ln512(const float* __restrict__ g_, const float* __restrict__ b_,
                                               u16* __restrict__ ws){
  const int t=threadIdx.x, wid=t>>6, lane=t&63;
  const int row = blockIdx.x*4 + wid;
  const float* xr = (const float*)(ws + WS_X) + row*512;
  f32x8 xv = *(const f32x8*)(xr + lane*8);
  float s=0.f, s2=0.f;
  #pragma unroll
  for (int i=0;i<8;i++){ s+=xv[i]; s2+=xv[i]*xv[i]; }
  #pragma unroll
  for (int m=1;m<64;m<<=1){ s += __shfl_xor(s,m,64); s2 += __shfl_xor(s2,m,64); }
  const float mean = s*(1.f/512.f);
  const float var  = s2*(1.f/512.f) - mean*mean;
  const float rstd = rsqrtf(var + 1e-5f);
  u16x8 yv;
  #pragma unroll
  for (int i=0;i<8;i++) yv[i] = f2b((xv[i]-mean)*rstd*g_[lane*8+i] + b_[lane*8+i]);
  *(u16x8*)(ws + WS_Y + row*512 + lane*8) = yv;
}

// ---------------- k_nmlp1: H2 = gelu(Y @ nW1 + nb1) ; col-slab, double-buffered T3-lite ----------------
__global__ __launch_bounds__(256) void k_nmlp1(const u16* __restrict__ A,
                                               const u16* __restrict__ BT,
                                               const float* __restrict__ b1,
                                               u16* __restrict__ H){
  __shared__ alignas(16) u16 SH2[16384];
  const int t=threadIdx.x, lid=t&63, w=t>>6, g=lid>>4, q=lid&15;
  const int r0 = blockIdx.x*128, n0 = blockIdx.y*128;
  const int wc3 = w*32;
  f32x4 acc[8][2] = {};
  #pragma unroll
  for (int j=0;j<2;j++){
    const int v = t + 256*j;
    const int row = v>>2, sg = (v&3)*8;
    gload16(A  + (r0+row)*512 + sg, SH2 + (w*64 + 256*j)*8);
    gload16(BT + (n0+row)*512 + sg, SH2 + 4096 + (w*64 + 256*j)*8);
  }
  __syncthreads();
  for (int ks=0; ks<16; ++ks){
    const int cur = ks & 1;
    if (ks < 15){
      const int kk = (ks+1)*32;
      const int nb = cur ^ 1;
      #pragma unroll
      for (int j=0;j<2;j++){
        const int v = t + 256*j;
        const int row = v>>2, sg = (v&3)*8;
        gload16(A  + (r0+row)*512 + kk + sg, SH2 + nb*8192 + (w*64 + 256*j)*8);
        gload16(BT + (n0+row)*512 + kk + sg, SH2 + nb*8192 + 4096 + (w*64 + 256*j)*8);
      }
    }
    const u16* As = SH2 + cur*8192;
    const u16* Bs = As + 4096;
    s16x8 bf_[2];
    #pragma unroll
    for (int j=0;j<2;j++) bf_[j] = *(const s16x8*)(Bs + (wc3 + j*16 + q)*32 + g*8);
    #pragma unroll
    for (int i=0;i<8;i++){
      s16x8 af = *(const s16x8*)(As + (i*16+q)*32 + g*8);
      #pragma unroll
      for (int j=0;j<2;j++) acc[i][j] = MFMA(af, bf_[j], acc[i][j]);
    }
    __syncthreads();
  }
  #pragma unroll
  for (int p=0;p<2;p++){
    __syncthreads();
    #pragma unroll
    for (int i2=0;i2<4;i2++)
      #pragma unroll
      for (int j=0;j<2;j++)
        #pragma unroll
        for (int r=0;r<4;r++){
          const int rl = i2*16 + g*4 + r;
          const int cl = wc3 + j*16 + q;
          SH2[rl*136 + cl] = f2b(gelu_fast(acc[p*4+i2][j][r] + b1[n0 + cl]));
        }
    __syncthreads();
    #pragma unroll
    for (int it=0; it<4; ++it){
      const int v = t + 256*it;
      const int rrow = v >> 4, sc = (v & 15)*8;
      *(u16x8*)(H + (r0 + p*64 + rrow)*2048 + n0 + sc) = *(const u16x8*)(SH2 + rrow*136 + sc);
    }
  }
}

// ---------------- k_nmlp2: out = X + H2 @ nW2 + nb2 ; 64x64 tile ----------------
__global__ __launch_bounds__(256) void k_nmlp2(const u16* __restrict__ A,
                                               const u16* __restrict__ BT,
                                               const float* __restrict__ b2,
                                               const float* __restrict__ Xf,
                                               float* __restrict__ out){
  __shared__ alignas(16) u16 As[64*32];
  __shared__ alignas(16) u16 Bs[64*32];
  const int t=threadIdx.x, lid=t&63, w=t>>6, g=lid>>4, q=lid&15;
  const int r0 = blockIdx.x*64, n0 = blockIdx.y*64;
  const int wr=(w>>1)*32, wc2=(w&1)*32;
  f32x4 acc[2][2] = {};
  for (int kk=0;kk<2048;kk+=32){
    __syncthreads();
    {
      const int row = t>>2, sg = (t&3)*8;
      gload16(A  + (r0+row)*2048 + kk + sg, As + (w*64)*8);
      gload16(BT + (n0+row)*2048 + kk + sg, Bs + (w*64)*8);
    }
    __syncthreads();
    s16x8 af[2], bf_[2];
    #pragma unroll
    for (int i=0;i<2;i++) af[i]  = *(const s16x8*)(As + (wr+i*16+q)*32 + g*8);
    #pragma unroll
    for (int j=0;j<2;j++) bf_[j] = *(const s16x8*)(Bs + (wc2+j*16+q)*32 + g*8);
    #pragma unroll
    for (int i=0;i<2;i++)
      #pragma unroll
      for (int j=0;j<2;j++) acc[i][j] = MFMA(af[i], bf_[j], acc[i][j]);
  }
  #pragma unroll
  for (int i=0;i<2;i++)
    #pragma unroll
    for (int j=0;j<2;j++)
      #pragma unroll
      for (int r=0;r<4;r++){
        const int row = r0 + wr + i*16 + g*4 + r;
        const int col = n0 + wc2 + j*16 + q;
        out[row*512 + col] = acc[i][j][r] + b2[col] + Xf[row*512 + col];
      }
}

extern "C" void kernel_launch(void* const* d_in, const int* in_sizes, int n_in,
                              void* d_out, int out_size, void* d_ws, size_t ws_size,
                              hipStream_t stream){
  (void)in_sizes; (void)n_in; (void)out_size; (void)ws_size;
  const float* node_repr = (const float*)d_in[0];
  const float* edge_repr = (const float*)d_in[1];
  const int* edge_index = (const int*)d_in[2];
  const int* edge_mask  = (const int*)d_in[3];
  const float* mask_bw = (const float*)d_in[4];
  u16* ws = (u16*)d_ws;

  P13 ps;
  const int srcIdx[13] = {5,10,12,17,19,16,22,25,27,6,7,14,20};
  for (int i=0;i<13;i++) ps.p[i] = (const float*)d_in[srcIdx[i]];

  hipLaunchKernelGGL(k_transpose, dim3(1120), dim3(256), 0, stream, ps, ws);
  hipLaunchKernelGGL(k_cvtnode, dim3(512), dim3(256), 0, stream, node_repr, ws + WS_H);
  hipLaunchKernelGGL(k_proj, dim3(32,28), dim3(256), 0, stream,
                     (const float*)d_in[15], (const float*)d_in[21], ws);
  hipLaunchKernelGGL(k_edgepre, dim3(1024), dim3(512), 0, stream,
                     edge_repr, edge_index, mask_bw,
                     (const float*)d_in[8], (const float*)d_in[9], ws);
  for (int grp=0; grp<2; ++grp){
    const u16* Ag = ws + WS_YE + grp*32768*256;
    u16* Hg = ws + WS_H;
    u16* msgg = ws + WS_MSG + grp*32768*256;
    const int* emg = edge_mask + grp*32768;
    hipLaunchKernelGGL(k_mlp1, dim3(256,8), dim3(256), 0, stream,
                       Ag, ws + WS_W1T, (const float*)d_in[11], Hg);
    hipLaunchKernelGGL(k_mlp2, dim3(256,2), dim3(256), 0, stream,
                       Hg, ws + WS_W2T, (const float*)d_in[13], emg, msgg);
  }
  // attention path: Tm GEMM -> ab GEMM -> light per-node kernel
  hipLaunchKernelGGL(k_tm, dim3(512,2), dim3(256), 0, stream,
                     ws + WS_MSG, ws + WS_WmT, ws + WS_H);
  hipLaunchKernelGGL(k_ab, dim3(512), dim3(256), 0, stream,
                     ws + WS_H, (const float*)d_in[18], (float*)(ws + WS_YE));
  hipLaunchKernelGGL(k_attn2, dim3(2048), dim3(256), 0, stream,
                     edge_mask, ws);
  hipLaunchKernelGGL(k_og, dim3(32,16), dim3(256), 0, stream, ws);
  hipLaunchKernelGGL(k_dh, dim3(32,8), dim3(256), 0, stream, node_repr, ws);
  hipLaunchKernelGGL(k_ln512, dim3(512), dim3(256), 0, stream,
                     (const float*)d_in[23], (const float*)d_in[24], ws);
  hipLaunchKernelGGL(k_nmlp1, dim3(16,16), dim3(256), 0, stream,
                     ws + WS_Y, ws + WS_nW1T, (const float*)d_in[26], ws + WS_H);
  hipLaunchKernelGGL(k_nmlp2, dim3(32,8), dim3(256), 0, stream,
                     ws + WS_H, ws + WS_nW2T, (const float*)d_in[28],
                     (const float*)(ws + WS_X), (float*)d_out);
}